// Round 11
// baseline (347.453 us; speedup 1.0000x reference)
//
#include <hip/hip_runtime.h>

#define D 4096
#define RANK 8

typedef float f4 __attribute__((ext_vector_type(4)));

// ===========================================================================
// Round 11: r10 body, natural register allocation (NO min-waves hint).
//   c[k] = sum_d x[d] * VnT[k][d]        (pass 1)
//   y[d] = x[d] - sum_k c[k] * B[k][d]   (pass 2, same wave, x from cache)
// Allocator law learned r3/r4/r8/r10: forcing min-waves either spills
// (r3: VGPR 32 + scratch, 5.6x traffic; r8: +420MB scratch) or serializes
// (r10: VGPR=32, vk[8] loads issued 2-3 at a time, MLP collapsed, 147us
// despite 73% occupancy). r7's 33% occupancy was GRID-limited (4096 waves),
// not VGPR-limited. So: 1 row/wave (8192 waves = 32/CU available) + natural
// VGPR (~55-64 -> ~6 waves/SIMD resident with full 9-deep MLP).
// Outstanding-loads/SIMD: r7 = 4x9 = 36, r10 = 8x2.5 = 20, r11 ~ 6x9 = 54.
// Declared risk: basis L2 traffic 2.1GB -> ~32 TB/s at 65us, near the
// 34.5 TB/s L2 ceiling; if we flatline ~70us at high occupancy that's L2.
// ===========================================================================

__global__ __launch_bounds__(1024) void hra_setup(
    const float* __restrict__ u_raw, float* __restrict__ vnT_out,
    float* __restrict__ B_out) {
  __shared__ float s_g[16][36];
  __shared__ float s_G[36];
  __shared__ float s_Gn[64];
  __shared__ float s_T[64];
  __shared__ float s_invn[8];

  const int t = threadIdx.x;
  const int lane = t & 63;
  const int wid = t >> 6;

  float v[4][8];
#pragma unroll
  for (int q = 0; q < 4; ++q) {
    const int d = 4 * t + q;
    const f4* p = (const f4*)(u_raw + (size_t)d * RANK);
    f4 a0 = p[0];
    f4 a1 = p[1];
    v[q][0] = a0.x; v[q][1] = a0.y; v[q][2] = a0.z; v[q][3] = a0.w;
    v[q][4] = a1.x; v[q][5] = a1.y; v[q][6] = a1.z; v[q][7] = a1.w;
  }

  {  // Gram partials (packed upper triangle)
    float g[36];
#pragma unroll
    for (int k = 0; k < 36; ++k) g[k] = 0.f;
#pragma unroll
    for (int q = 0; q < 4; ++q) {
      int idx = 0;
#pragma unroll
      for (int i = 0; i < 8; ++i)
#pragma unroll
        for (int j = i; j < 8; ++j)
          g[idx++] += v[q][i] * v[q][j];
    }
#pragma unroll
    for (int off = 32; off >= 1; off >>= 1) {
#pragma unroll
      for (int k = 0; k < 36; ++k)
        g[k] += __shfl_xor(g[k], off, 64);
    }
    if (lane == 0) {
#pragma unroll
      for (int k = 0; k < 36; ++k) s_g[wid][k] = g[k];
    }
  }
  __syncthreads();

  if (t < 36) {
    float s = 0.f;
#pragma unroll
    for (int w2 = 0; w2 < 16; ++w2) s += s_g[w2][t];
    s_G[t] = s;
  }
  __syncthreads();

  if (t < 8) {
    const int dix[8] = {0, 8, 15, 21, 26, 30, 33, 35};
    s_invn[t] = rsqrtf(s_G[dix[t]]);
  }
  __syncthreads();

  if (t < 64) {
    const int i = t >> 3, j = t & 7;
    const int ii = i < j ? i : j;
    const int jj = i < j ? j : i;
    const int idx = ii * 8 - (ii * (ii - 1)) / 2 + (jj - ii);
    s_Gn[t] = s_G[idx] * s_invn[i] * s_invn[j];
  }
  __syncthreads();

  if (t < 8) {  // column-parallel WY recurrence
    const int j = t;
    for (int k = 0; k < j; ++k) s_T[k * 8 + j] = 0.f;
    s_T[j * 8 + j] = 2.f;
    for (int k = j + 1; k < 8; ++k) {
      float s = 0.f;
      for (int l = j; l < k; ++l) s += s_Gn[k * 8 + l] * s_T[l * 8 + j];
      s_T[k * 8 + j] = -2.f * s;
    }
  }
  __syncthreads();

  // normalize V
  {
    float invn[8];
#pragma unroll
    for (int i = 0; i < 8; ++i) invn[i] = s_invn[i];
#pragma unroll
    for (int q = 0; q < 4; ++q)
#pragma unroll
      for (int i = 0; i < 8; ++i) v[q][i] *= invn[i];
  }

  // VnT[k][d] (k-major): coalesced f4 stores
#pragma unroll
  for (int k = 0; k < 8; ++k) {
    f4 b = {v[0][k], v[1][k], v[2][k], v[3][k]};
    *(f4*)(vnT_out + (size_t)k * D + 4 * t) = b;
  }

  // B[k][d] = sum_j Vn[d][j] * T[j][k]
#pragma unroll
  for (int k = 0; k < 8; ++k) {
    float Tk[8];
#pragma unroll
    for (int j = 0; j < 8; ++j) Tk[j] = s_T[j * 8 + k];
    float bq[4];
#pragma unroll
    for (int q = 0; q < 4; ++q) {
      float s = 0.f;
#pragma unroll
      for (int j = 0; j < 8; ++j) s += v[q][j] * Tk[j];
      bq[q] = s;
    }
    f4 b = {bq[0], bq[1], bq[2], bq[3]};
    *(f4*)(B_out + (size_t)k * D + 4 * t) = b;
  }
}

// ---------------------------------------------------------------------------
// Fused dots+apply. ONE row per wave; no barriers; simple body; natural
// VGPR allocation (no min-waves hint -- see allocator law above).
// ---------------------------------------------------------------------------
#define FK_BLOCK 256
__global__ __launch_bounds__(FK_BLOCK) void hra_fused2(
    const float* __restrict__ x_in, const float* __restrict__ vnT,
    const float* __restrict__ B, float* __restrict__ y, int rows) {
  const int lane = threadIdx.x & 63;
  const int r = blockIdx.x * (FK_BLOCK / 64) + (threadIdx.x >> 6);
  if (r >= rows) return;

  const float* x0 = x_in + (size_t)r * D;

  // ---- pass 1: c = VnT * x (all loads coalesced; basis L2-hot) ----
  float acc[8];
#pragma unroll
  for (int i = 0; i < 8; ++i) acc[i] = 0.f;

#pragma unroll 2
  for (int it = 0; it < 16; ++it) {
    const int d = it * 256 + lane * 4;
    f4 a = *(const f4*)(x0 + d);
    f4 vk[8];
#pragma unroll
    for (int k = 0; k < 8; ++k)
      vk[k] = *(const f4*)(vnT + (size_t)k * D + d);
#pragma unroll
    for (int k = 0; k < 8; ++k)
      acc[k] += a.x * vk[k].x + a.y * vk[k].y + a.z * vk[k].z + a.w * vk[k].w;
  }

  // ---- wave butterfly: full c in every lane (48 shfl) ----
#pragma unroll
  for (int off = 32; off >= 1; off >>= 1) {
#pragma unroll
    for (int i = 0; i < 8; ++i)
      acc[i] += __shfl_xor(acc[i], off, 64);
  }

  // ---- pass 2: y = x - sum_k c_k B_k (x re-read from L2/L3) ----
  float* y0 = y + (size_t)r * D;

#pragma unroll 2
  for (int it = 0; it < 16; ++it) {
    const int d = it * 256 + lane * 4;
    f4 a = *(const f4*)(x0 + d);
    f4 s = {0.f, 0.f, 0.f, 0.f};
#pragma unroll
    for (int k = 0; k < 8; ++k) {
      f4 Bk = *(const f4*)(B + (size_t)k * D + d);
      s += acc[k] * Bk;
    }
    f4 o = a - s;
    __builtin_nontemporal_store(o, (f4*)(y0 + d));
  }
}

extern "C" void kernel_launch(void* const* d_in, const int* in_sizes, int n_in,
                              void* d_out, int out_size, void* d_ws, size_t ws_size,
                              hipStream_t stream) {
  const float* x_in = (const float*)d_in[0];
  const float* u = (const float*)d_in[1];
  float* y = (float*)d_out;
  (void)n_in; (void)out_size; (void)ws_size;

  const int rows = in_sizes[0] / D;  // 8192

  float* vnT = (float*)d_ws;           // 8*D floats = 128 KB
  float* B = vnT + (size_t)RANK * D;   // 8*D floats = 128 KB

  hipLaunchKernelGGL(hra_setup, dim3(1), dim3(1024), 0, stream, u, vnT, B);

  // one wave per row: rows waves, 4 waves/block
  const int grid = rows / (FK_BLOCK / 64);  // 2048
  hipLaunchKernelGGL(hra_fused2, dim3(grid), dim3(FK_BLOCK), 0, stream,
                     x_in, vnT, B, y, rows);
}